// Round 12
// baseline (2851.896 us; speedup 1.0000x reference)
//
#include <hip/hip_runtime.h>
#include <stdint.h>

#define TT 12
#define NITERS 10
#define NCAND 1000
#define AD 6
#define BD 16
#define HD 200
#define ZD 30
#define NROWS 16000
#define NELEM 1152000u

// ws layout (u32/float offsets)
#define OFF_WSW  0u          // u32[53248]  W_all pre-split+swizzled B-frags [hl][13][8][64][4]
#define OFF_WZSW 53248u      // u32[7168]   Wz  [hl][2][7][64][4]
#define OFF_WRSW 60416u      // u32[4096]   Wr' [hl][8][64][4] (col0 only)
#define OFF_MEAN 64512u      // f32[12][16][8]
#define OFF_STD  66048u      // f32[12][16][8]
#define OFF_ACT  67584u      // f32[12][16000][8]
#define OFF_RET  1603584u    // f32[16000]
#define OFF_TOPK 1619584u    // int[16][100]

typedef __attribute__((ext_vector_type(8))) short short8v;
typedef __attribute__((ext_vector_type(4))) float f32x4;

// ---------------- threefry2x32 (JAX-exact) ----------------
__host__ __device__ __forceinline__ uint32_t tf_rotl(uint32_t x, int r) {
  return (x << r) | (x >> (32 - r));
}
__host__ __device__ __forceinline__ void tf2x32(uint32_t k0, uint32_t k1,
                                                uint32_t& x0, uint32_t& x1) {
  uint32_t k2 = k0 ^ k1 ^ 0x1BD11BDAu;
  x0 += k0; x1 += k1;
  x0 += x1; x1 = tf_rotl(x1, 13); x1 ^= x0;
  x0 += x1; x1 = tf_rotl(x1, 15); x1 ^= x0;
  x0 += x1; x1 = tf_rotl(x1, 26); x1 ^= x0;
  x0 += x1; x1 = tf_rotl(x1,  6); x1 ^= x0;
  x0 += k1; x1 += k2 + 1u;
  x0 += x1; x1 = tf_rotl(x1, 17); x1 ^= x0;
  x0 += x1; x1 = tf_rotl(x1, 29); x1 ^= x0;
  x0 += x1; x1 = tf_rotl(x1, 16); x1 ^= x0;
  x0 += x1; x1 = tf_rotl(x1, 24); x1 ^= x0;
  x0 += k2; x1 += k0 + 2u;
  x0 += x1; x1 = tf_rotl(x1, 13); x1 ^= x0;
  x0 += x1; x1 = tf_rotl(x1, 15); x1 ^= x0;
  x0 += x1; x1 = tf_rotl(x1, 26); x1 ^= x0;
  x0 += x1; x1 = tf_rotl(x1,  6); x1 ^= x0;
  x0 += k0; x1 += k1 + 3u;
  x0 += x1; x1 = tf_rotl(x1, 17); x1 ^= x0;
  x0 += x1; x1 = tf_rotl(x1, 29); x1 ^= x0;
  x0 += x1; x1 = tf_rotl(x1, 16); x1 ^= x0;
  x0 += x1; x1 = tf_rotl(x1, 24); x1 ^= x0;
  x0 += k1; x1 += k2 + 4u;
  x0 += x1; x1 = tf_rotl(x1, 13); x1 ^= x0;
  x0 += x1; x1 = tf_rotl(x1, 15); x1 ^= x0;
  x0 += x1; x1 = tf_rotl(x1, 26); x1 ^= x0;
  x0 += x1; x1 = tf_rotl(x1,  6); x1 ^= x0;
  x0 += k2; x1 += k0 + 5u;
}

__device__ __forceinline__ float bits_to_normal(uint32_t bits) {
  uint32_t fb = (bits >> 9) | 0x3F800000u;
  float f = __uint_as_float(fb) - 1.0f;          // [0,1)
  float u = f * 2.0f - 0.99999994f;
  u = fmaxf(-0.99999994f, u);
  float w = -log1pf(-u * u);
  float p;
  if (w < 5.0f) {
    w = w - 2.5f;
    p = 2.81022636e-08f;
    p = fmaf(p, w, 3.43273939e-07f);
    p = fmaf(p, w, -3.5233877e-06f);
    p = fmaf(p, w, -4.39150654e-06f);
    p = fmaf(p, w, 0.00021858087f);
    p = fmaf(p, w, -0.00125372503f);
    p = fmaf(p, w, -0.00417768164f);
    p = fmaf(p, w, 0.246640727f);
    p = fmaf(p, w, 1.50140941f);
  } else {
    w = sqrtf(w) - 3.0f;
    p = -0.000200214257f;
    p = fmaf(p, w, 0.000100950558f);
    p = fmaf(p, w, 0.00134934322f);
    p = fmaf(p, w, -0.00367342844f);
    p = fmaf(p, w, 0.00573950773f);
    p = fmaf(p, w, -0.0076224613f);
    p = fmaf(p, w, 0.00943887047f);
    p = fmaf(p, w, 1.00167406f);
    p = fmaf(p, w, 2.83297682f);
  }
  return 1.41421354f * (p * u);
}

// bf16 round-to-nearest-even (returns 16-bit pattern)
__device__ __forceinline__ uint32_t bf16rne(float x) {
  uint32_t u = __float_as_uint(x);
  return (u + 0x7FFFu + ((u >> 16) & 1u)) >> 16;
}

// ---------------- prep: split+swizzle weights into B-frag order ----------------
__global__ __launch_bounds__(256) void k_prep(const float* Wb, const float* Ws_,
                                              const float* Wa, const float* Wz,
                                              const float* Wr, float* ws) {
  int i = blockIdx.x * 256 + threadIdx.x;
  uint32_t* wsu = (uint32_t*)ws;
  if (i < 53248) {
    int d = i & 3; int t = i >> 2;
    int lane = t & 63; t >>= 6;
    int ks = t & 7; t >>= 3;
    int nt = t % 13; int hl = t / 13;
    int col = nt * 16 + (lane & 15);
    int kb = ks * 32 + (lane >> 4) * 8 + d * 2;
    uint32_t out = 0;
    for (int e = 0; e < 2; ++e) {
      int k = kb + e;
      float v = 0.f;
      if (col < 200) {
        if (k < 200)      v = Wb[k * 200 + col];
        else if (k < 230) v = Ws_[(k - 200) * 200 + col];
        else if (k < 236) v = Wa[(k - 230) * 200 + col];
      }
      uint32_t hi = bf16rne(v);
      float hf = __uint_as_float(hi << 16);
      uint32_t lo = bf16rne(v - hf);
      uint32_t bits = (hl == 0) ? hi : lo;
      out |= (bits & 0xFFFFu) << (16 * e);
    }
    wsu[OFF_WSW + i] = out;
  } else if (i < 60416) {
    int j = i - 53248;
    int d = j & 3; int t = j >> 2;
    int lane = t & 63; t >>= 6;
    int ks = t % 7; t /= 7;
    int nt = t & 1; int hl = t >> 1;
    int col = nt * 16 + (lane & 15);
    int kb = ks * 32 + (lane >> 4) * 8 + d * 2;
    uint32_t out = 0;
    for (int e = 0; e < 2; ++e) {
      int k = kb + e;
      float v = (k < 200 && col < 30) ? Wz[k * 30 + col] : 0.f;
      uint32_t hi = bf16rne(v);
      float hf = __uint_as_float(hi << 16);
      uint32_t lo = bf16rne(v - hf);
      uint32_t bits = (hl == 0) ? hi : lo;
      out |= (bits & 0xFFFFu) << (16 * e);
    }
    wsu[OFF_WZSW + j] = out;
  } else if (i < 64512) {
    int j = i - 60416;
    int d = j & 3; int t = j >> 2;
    int lane = t & 63; t >>= 6;
    int ks = t & 7; int hl = t >> 3;
    int col = lane & 15;
    int kb = ks * 32 + (lane >> 4) * 8 + d * 2;
    uint32_t out = 0;
    for (int e = 0; e < 2; ++e) {
      int k = kb + e;
      float v = (col == 0 && k < 230) ? Wr[k] : 0.f;
      uint32_t hi = bf16rne(v);
      float hf = __uint_as_float(hi << 16);
      uint32_t lo = bf16rne(v - hf);
      uint32_t bits = (hl == 0) ? hi : lo;
      out |= (bits & 0xFFFFu) << (16 * e);
    }
    wsu[OFF_WRSW + j] = out;
  } else if (i < 66048) {
    ws[i] = 0.f;   // mean
  } else if (i < 67584) {
    ws[i] = 1.f;   // std
  }
}

// ---------------- actions = mean + std * normal(threefry) ----------------
__global__ __launch_bounds__(256) void k_actions(uint32_t k0, uint32_t k1, float* ws) {
  uint32_t idx = blockIdx.x * 256u + threadIdx.x;
  if (idx >= NELEM) return;
  uint32_t x0 = 0u, x1 = idx;
  tf2x32(k0, k1, x0, x1);
  float z = bits_to_normal(x0 ^ x1);
  uint32_t a = idx % 6u;  uint32_t q = idx / 6u;
  uint32_t c = q % 1000u; uint32_t q2 = q / 1000u;
  uint32_t b = q2 % 16u;  uint32_t t = q2 / 16u;
  uint32_t mi = (t * 16u + b) * 8u + a;
  float m = ws[OFF_MEAN + mi];
  float s = ws[OFF_STD + mi];
  ws[OFF_ACT + ((size_t)t * NROWS + b * 1000u + c) * 8u + a] = fmaf(s, z, m);
}

// ---------------- full 12-step rollout: WAVE-PRIVATE, ZERO BARRIERS ----------------
// 64 rows/block, 4 waves; each wave owns 16 rows (1 M-tile) END-TO-END:
// stage-1 over ALL 13 N-tiles, stage-2 both col-tiles, reward, action writes.
// All LDS traffic is wave-private -> program order suffices (no __syncthreads,
// no cross-wave races — the R8/R9 failure class is structurally impossible).
// Per-element MFMA chains IDENTICAL to validated R7/R10 (same k-order, same
// Al·Bl, Ah·Bl, Al·Bh, Ah·Bh order) -> bit-identical output.
__global__ __launch_bounds__(256) void k_roll(float* __restrict__ ws,
                                              const float* __restrict__ belief,
                                              const float* __restrict__ state,
                                              const float* __restrict__ bbp,
                                              const float* __restrict__ bzp,
                                              const float* __restrict__ brp) {
  __shared__ unsigned short xh[4 * 16 * 280];   // per-wave bf16 hi chunks
  __shared__ unsigned short xl[4 * 16 * 280];   // per-wave bf16 lo chunks

  const int tid = threadIdx.x;
  const int wv = tid >> 6;
  const int ln = tid & 63;
  const int r = ln & 15;
  const int kh = ln >> 4;
  const int grow0 = blockIdx.x * 64 + wv * 16;  // wave's global row base
  const int xb = wv * 16 * 280;                 // wave's LDS base
  const uint32_t* __restrict__ wsu = (const uint32_t*)ws;

  // per-lane constants
  float bbv[13];
#pragma unroll
  for (int j = 0; j < 13; ++j) {
    int col = j * 16 + r;
    bbv[j] = (col < 200) ? bbp[col] : 0.f;
  }
  float bzz0, bzz1;
  bzz0 = (r < 16) ? ((0 * 16 + r < 30) ? bzp[r] : 0.f) : 0.f;
  bzz1 = (16 + r < 30) ? bzp[16 + r] : 0.f;
  const float br0 = brp[0];

  // init x for own 16 rows: k<200 belief, 200..230 state, rest 0
  for (int idx = ln; idx < 16 * 256; idx += 64) {
    int row = idx >> 8, k = idx & 255;
    int b = (grow0 + row) / 1000;
    float v = 0.f;
    if (k < 200) v = belief[b * 200 + k];
    else if (k < 230) v = state[b * 30 + (k - 200)];
    uint32_t hi = bf16rne(v);
    float hf = __uint_as_float(hi << 16);
    uint32_t lo = bf16rne(v - hf);
    xh[xb + row * 280 + k] = (unsigned short)hi;
    xl[xb + row * 280 + k] = (unsigned short)lo;
  }

  // t=0 actions for own rows (wave-private; program order after init)
  {
    const float* actp = ws + OFF_ACT + (size_t)grow0 * 8;
    for (int idx = ln; idx < 96; idx += 64) {
      int row = idx / 6, a = idx - row * 6;
      float v = actp[row * 8 + a];
      uint32_t hi = bf16rne(v);
      float hf = __uint_as_float(hi << 16);
      uint32_t lo = bf16rne(v - hf);
      xh[xb + row * 280 + 230 + a] = (unsigned short)hi;
      xl[xb + row * 280 + 230 + a] = (unsigned short)lo;
    }
  }

  f32x4 racc = {0.f, 0.f, 0.f, 0.f};

#pragma unroll 1
  for (int t = 0; t < TT; ++t) {
    // ---- stage 1: h = tanh(x @ W_all + bb); 1 M-tile x ALL 13 N-tiles ----
    f32x4 acc[13];
#pragma unroll
    for (int j = 0; j < 13; ++j) {
      f32x4 c = {bbv[j], bbv[j], bbv[j], bbv[j]};
      acc[j] = c;
    }

#pragma unroll 2
    for (int ks = 0; ks < 8; ++ks) {
      const int off = xb + r * 280 + ks * 32 + kh * 8;
      short8v Ah = *(const short8v*)&xh[off];
      short8v Al = *(const short8v*)&xl[off];
#pragma unroll
      for (int j = 0; j < 13; ++j) {
        const short8v Bh = *(const short8v*)(wsu + OFF_WSW + (((0 * 13 + j) * 8 + ks) * 64 + ln) * 4);
        const short8v Bl = *(const short8v*)(wsu + OFF_WSW + (((1 * 13 + j) * 8 + ks) * 64 + ln) * 4);
        f32x4 c = acc[j];
        c = __builtin_amdgcn_mfma_f32_16x16x32_bf16(Al, Bl, c, 0, 0, 0);
        c = __builtin_amdgcn_mfma_f32_16x16x32_bf16(Ah, Bl, c, 0, 0, 0);
        c = __builtin_amdgcn_mfma_f32_16x16x32_bf16(Al, Bh, c, 0, 0, 0);
        c = __builtin_amdgcn_mfma_f32_16x16x32_bf16(Ah, Bh, c, 0, 0, 0);
        acc[j] = c;
      }
    }

    // h epilogue: tanh, split, write back (D: row=(ln>>4)*4+reg, col=ln&15)
#pragma unroll
    for (int j = 0; j < 13; ++j) {
      int col = j * 16 + r;
      if (col < 200) {
#pragma unroll
        for (int reg = 0; reg < 4; ++reg) {
          int row = kh * 4 + reg;
          float h = tanhf(acc[j][reg]);
          uint32_t hi = bf16rne(h);
          float hf = __uint_as_float(hi << 16);
          uint32_t lo = bf16rne(h - hf);
          xh[xb + row * 280 + col] = (unsigned short)hi;
          xl[xb + row * 280 + col] = (unsigned short)lo;
        }
      }
    }
    // wave-private LDS: program order (lgkmcnt) covers write->read; no barrier

    // ---- stage 2: s = tanh(h @ Wz + bz); both col-tiles in this wave ----
    f32x4 acc2a = {bzz0, bzz0, bzz0, bzz0};
    f32x4 acc2b = {bzz1, bzz1, bzz1, bzz1};
#pragma unroll
    for (int ks = 0; ks < 7; ++ks) {          // K=224; k>=200 x Wz==0 benign
      int off = xb + r * 280 + ks * 32 + kh * 8;
      short8v Ah2 = *(const short8v*)&xh[off];
      short8v Al2 = *(const short8v*)&xl[off];
      {
        const short8v Bh = *(const short8v*)(wsu + OFF_WZSW + (((0 * 2 + 0) * 7 + ks) * 64 + ln) * 4);
        const short8v Bl = *(const short8v*)(wsu + OFF_WZSW + (((1 * 2 + 0) * 7 + ks) * 64 + ln) * 4);
        acc2a = __builtin_amdgcn_mfma_f32_16x16x32_bf16(Al2, Bl, acc2a, 0, 0, 0);
        acc2a = __builtin_amdgcn_mfma_f32_16x16x32_bf16(Ah2, Bl, acc2a, 0, 0, 0);
        acc2a = __builtin_amdgcn_mfma_f32_16x16x32_bf16(Al2, Bh, acc2a, 0, 0, 0);
        acc2a = __builtin_amdgcn_mfma_f32_16x16x32_bf16(Ah2, Bh, acc2a, 0, 0, 0);
      }
      {
        const short8v Bh = *(const short8v*)(wsu + OFF_WZSW + (((0 * 2 + 1) * 7 + ks) * 64 + ln) * 4);
        const short8v Bl = *(const short8v*)(wsu + OFF_WZSW + (((1 * 2 + 1) * 7 + ks) * 64 + ln) * 4);
        acc2b = __builtin_amdgcn_mfma_f32_16x16x32_bf16(Al2, Bl, acc2b, 0, 0, 0);
        acc2b = __builtin_amdgcn_mfma_f32_16x16x32_bf16(Ah2, Bl, acc2b, 0, 0, 0);
        acc2b = __builtin_amdgcn_mfma_f32_16x16x32_bf16(Al2, Bh, acc2b, 0, 0, 0);
        acc2b = __builtin_amdgcn_mfma_f32_16x16x32_bf16(Ah2, Bh, acc2b, 0, 0, 0);
      }
    }
    // s epilogue: write k 200..230 (col-tile 0: cols 0..16, tile 1: 16..30)
    {
      int col = r;                      // j2=0
#pragma unroll
      for (int reg = 0; reg < 4; ++reg) {
        int row = kh * 4 + reg;
        float s = tanhf(acc2a[reg]);
        uint32_t hi = bf16rne(s);
        float hf = __uint_as_float(hi << 16);
        uint32_t lo = bf16rne(s - hf);
        xh[xb + row * 280 + 200 + col] = (unsigned short)hi;
        xl[xb + row * 280 + 200 + col] = (unsigned short)lo;
      }
      int col2 = 16 + r;                // j2=1
      if (col2 < 30) {
#pragma unroll
        for (int reg = 0; reg < 4; ++reg) {
          int row = kh * 4 + reg;
          float s = tanhf(acc2b[reg]);
          uint32_t hi = bf16rne(s);
          float hf = __uint_as_float(hi << 16);
          uint32_t lo = bf16rne(s - hf);
          xh[xb + row * 280 + 200 + col2] = (unsigned short)hi;
          xl[xb + row * 280 + 200 + col2] = (unsigned short)lo;
        }
      }
    }

    // ---- reward: racc += [h|s] @ Wr' (col 0); full ks chain in this wave ----
#pragma unroll
    for (int ks = 0; ks < 8; ++ks) {
      int off = xb + r * 280 + ks * 32 + kh * 8;
      short8v Ah3 = *(const short8v*)&xh[off];
      short8v Al3 = *(const short8v*)&xl[off];
      const short8v Bh = *(const short8v*)(wsu + OFF_WRSW + ((0 * 8 + ks) * 64 + ln) * 4);
      const short8v Bl = *(const short8v*)(wsu + OFF_WRSW + ((1 * 8 + ks) * 64 + ln) * 4);
      racc = __builtin_amdgcn_mfma_f32_16x16x32_bf16(Al3, Bl, racc, 0, 0, 0);
      racc = __builtin_amdgcn_mfma_f32_16x16x32_bf16(Ah3, Bl, racc, 0, 0, 0);
      racc = __builtin_amdgcn_mfma_f32_16x16x32_bf16(Al3, Bh, racc, 0, 0, 0);
      racc = __builtin_amdgcn_mfma_f32_16x16x32_bf16(Ah3, Bh, racc, 0, 0, 0);
    }

    // ---- actions for t+1 (wave-private writes; ordered after reward reads) ----
    if (t + 1 < TT) {
      const float* actp = ws + OFF_ACT + ((size_t)(t + 1) * NROWS + grow0) * 8;
      for (int idx = ln; idx < 96; idx += 64) {
        int row = idx / 6, a = idx - row * 6;
        float v = actp[row * 8 + a];
        uint32_t hi = bf16rne(v);
        float hf = __uint_as_float(hi << 16);
        uint32_t lo = bf16rne(v - hf);
        xh[xb + row * 280 + 230 + a] = (unsigned short)hi;
        xl[xb + row * 280 + 230 + a] = (unsigned short)lo;
      }
    }
  }

  if (r == 0) {
#pragma unroll
    for (int reg = 0; reg < 4; ++reg) {
      int row = kh * 4 + reg;
      ws[OFF_RET + grow0 + row] = racc[reg] + 12.0f * br0;
    }
  }
}

// ---------------- top-k via full bitonic sort (desc, ties by index) ----------------
__global__ __launch_bounds__(1024) void k_topk(float* ws) {
  __shared__ float sv[1024];
  __shared__ int si[1024];
  const int b = blockIdx.x, tid = threadIdx.x;
  const float* ret = ws + OFF_RET + b * 1000;
  sv[tid] = (tid < 1000) ? ret[tid] : -3.0e38f;
  si[tid] = tid;
  __syncthreads();
  for (int k = 2; k <= 1024; k <<= 1) {
    for (int j = k >> 1; j > 0; j >>= 1) {
      int ixj = tid ^ j;
      if (ixj > tid) {
        float v1 = sv[tid], v2 = sv[ixj];
        int i1 = si[tid], i2 = si[ixj];
        bool gt = (v1 < v2) || (v1 == v2 && i1 > i2);
        bool up = ((tid & k) == 0);
        if (up ? gt : !gt) {
          sv[tid] = v2; sv[ixj] = v1;
          si[tid] = i2; si[ixj] = i1;
        }
      }
      __syncthreads();
    }
  }
  int* topk = (int*)(ws + OFF_TOPK);
  if (tid < 100) topk[b * 100 + tid] = si[tid];
}

// ---------------- mean/std over elites: one wave per (t,b,a) ----------------
__global__ __launch_bounds__(256) void k_meanstd(float* ws) {
  const int g = blockIdx.x * 4 + (threadIdx.x >> 6);  // 0..1151
  const int ln = threadIdx.x & 63;
  const int t = g / 96; const int rem = g - t * 96;
  const int b = rem / 6; const int a = rem - b * 6;
  const int* topk = (const int*)(ws + OFF_TOPK) + b * 100;
  const float* act = ws + OFF_ACT + (size_t)t * NROWS * 8;
  const bool h2 = (ln < 36);
  int c1 = topk[ln];
  float x1 = act[((size_t)b * 1000 + c1) * 8 + a];
  float x2 = 0.f;
  if (h2) { int cc = topk[ln + 64]; x2 = act[((size_t)b * 1000 + cc) * 8 + a]; }
  float s = x1 + x2;
#pragma unroll
  for (int m = 1; m < 64; m <<= 1) s += __shfl_xor(s, m, 64);
  const float mean = s / 100.0f;
  float d = x1 - mean; float qq = d * d;
  if (h2) { float d2 = x2 - mean; qq += d2 * d2; }
#pragma unroll
  for (int m = 1; m < 64; m <<= 1) qq += __shfl_xor(qq, m, 64);
  if (ln == 0) {
    ws[OFF_MEAN + ((size_t)t * 16 + b) * 8 + a] = mean;
    ws[OFF_STD  + ((size_t)t * 16 + b) * 8 + a] = sqrtf(qq / 100.0f);
  }
}

__global__ void k_out(const float* ws, float* out) {
  int i = threadIdx.x;
  if (i < 96) out[i] = ws[OFF_MEAN + (i / 6) * 8 + (i % 6)];
}

extern "C" void kernel_launch(void* const* d_in, const int* in_sizes, int n_in,
                              void* d_out, int out_size, void* d_ws, size_t ws_size,
                              hipStream_t stream) {
  const float* belief = (const float*)d_in[0];
  const float* state  = (const float*)d_in[1];
  const float* Wb  = (const float*)d_in[2];
  const float* Ws_ = (const float*)d_in[3];
  const float* Wa  = (const float*)d_in[4];
  const float* bb  = (const float*)d_in[5];
  const float* Wz  = (const float*)d_in[6];
  const float* bz  = (const float*)d_in[7];
  const float* Wr  = (const float*)d_in[8];
  const float* br  = (const float*)d_in[9];
  float* ws = (float*)d_ws;   // needs ~6.5 MB

  k_prep<<<264, 256, 0, stream>>>(Wb, Ws_, Wa, Wz, Wr, ws);

  for (int it = 0; it < NITERS; ++it) {
    uint32_t f0 = 0u, f1 = (uint32_t)it;
    tf2x32(0u, 42u, f0, f1);
    k_actions<<<4500, 256, 0, stream>>>(f0, f1, ws);
    k_roll<<<250, 256, 0, stream>>>(ws, belief, state, bb, bz, br);
    k_topk<<<16, 1024, 0, stream>>>(ws);
    k_meanstd<<<288, 256, 0, stream>>>(ws);
  }
  k_out<<<1, 128, 0, stream>>>(ws, (float*)d_out);
}

// Round 13
// 1707.344 us; speedup vs baseline: 1.6704x; 1.6704x over previous
//
#include <hip/hip_runtime.h>
#include <stdint.h>

#define TT 12
#define NITERS 10
#define NCAND 1000
#define AD 6
#define BD 16
#define HD 200
#define ZD 30
#define NROWS 16000
#define NELEM 1152000u

// ws layout (u32/float offsets)
#define OFF_WSW  0u          // u32[53248]  W_all split+swizzled B-frags [hl][13][8][64][4]
#define OFF_WZSW 53248u      // u32[7168]   [Wz | Wr_h@col30] [hl][2][7][64][4]
#define OFF_MEAN 64512u      // f32[12][16][8]
#define OFF_STD  66048u      // f32[12][16][8]
#define OFF_ACT  67584u      // f32[12][16000][8]
#define OFF_RET  1603584u    // f32[16000]

typedef __attribute__((ext_vector_type(8))) short short8v;
typedef __attribute__((ext_vector_type(4))) float f32x4;

// ---------------- threefry2x32 (JAX-exact) ----------------
__host__ __device__ __forceinline__ uint32_t tf_rotl(uint32_t x, int r) {
  return (x << r) | (x >> (32 - r));
}
__host__ __device__ __forceinline__ void tf2x32(uint32_t k0, uint32_t k1,
                                                uint32_t& x0, uint32_t& x1) {
  uint32_t k2 = k0 ^ k1 ^ 0x1BD11BDAu;
  x0 += k0; x1 += k1;
  x0 += x1; x1 = tf_rotl(x1, 13); x1 ^= x0;
  x0 += x1; x1 = tf_rotl(x1, 15); x1 ^= x0;
  x0 += x1; x1 = tf_rotl(x1, 26); x1 ^= x0;
  x0 += x1; x1 = tf_rotl(x1,  6); x1 ^= x0;
  x0 += k1; x1 += k2 + 1u;
  x0 += x1; x1 = tf_rotl(x1, 17); x1 ^= x0;
  x0 += x1; x1 = tf_rotl(x1, 29); x1 ^= x0;
  x0 += x1; x1 = tf_rotl(x1, 16); x1 ^= x0;
  x0 += x1; x1 = tf_rotl(x1, 24); x1 ^= x0;
  x0 += k2; x1 += k0 + 2u;
  x0 += x1; x1 = tf_rotl(x1, 13); x1 ^= x0;
  x0 += x1; x1 = tf_rotl(x1, 15); x1 ^= x0;
  x0 += x1; x1 = tf_rotl(x1, 26); x1 ^= x0;
  x0 += x1; x1 = tf_rotl(x1,  6); x1 ^= x0;
  x0 += k0; x1 += k1 + 3u;
  x0 += x1; x1 = tf_rotl(x1, 17); x1 ^= x0;
  x0 += x1; x1 = tf_rotl(x1, 29); x1 ^= x0;
  x0 += x1; x1 = tf_rotl(x1, 16); x1 ^= x0;
  x0 += x1; x1 = tf_rotl(x1, 24); x1 ^= x0;
  x0 += k1; x1 += k2 + 4u;
  x0 += x1; x1 = tf_rotl(x1, 13); x1 ^= x0;
  x0 += x1; x1 = tf_rotl(x1, 15); x1 ^= x0;
  x0 += x1; x1 = tf_rotl(x1, 26); x1 ^= x0;
  x0 += x1; x1 = tf_rotl(x1,  6); x1 ^= x0;
  x0 += k2; x1 += k0 + 5u;
}

__device__ __forceinline__ float bits_to_normal(uint32_t bits) {
  uint32_t fb = (bits >> 9) | 0x3F800000u;
  float f = __uint_as_float(fb) - 1.0f;          // [0,1)
  float u = f * 2.0f - 0.99999994f;
  u = fmaxf(-0.99999994f, u);
  float w = -log1pf(-u * u);
  float p;
  if (w < 5.0f) {
    w = w - 2.5f;
    p = 2.81022636e-08f;
    p = fmaf(p, w, 3.43273939e-07f);
    p = fmaf(p, w, -3.5233877e-06f);
    p = fmaf(p, w, -4.39150654e-06f);
    p = fmaf(p, w, 0.00021858087f);
    p = fmaf(p, w, -0.00125372503f);
    p = fmaf(p, w, -0.00417768164f);
    p = fmaf(p, w, 0.246640727f);
    p = fmaf(p, w, 1.50140941f);
  } else {
    w = sqrtf(w) - 3.0f;
    p = -0.000200214257f;
    p = fmaf(p, w, 0.000100950558f);
    p = fmaf(p, w, 0.00134934322f);
    p = fmaf(p, w, -0.00367342844f);
    p = fmaf(p, w, 0.00573950773f);
    p = fmaf(p, w, -0.0076224613f);
    p = fmaf(p, w, 0.00943887047f);
    p = fmaf(p, w, 1.00167406f);
    p = fmaf(p, w, 2.83297682f);
  }
  return 1.41421354f * (p * u);
}

// bf16 round-to-nearest-even (returns 16-bit pattern)
__device__ __forceinline__ uint32_t bf16rne(float x) {
  uint32_t u = __float_as_uint(x);
  return (u + 0x7FFFu + ((u >> 16) & 1u)) >> 16;
}

// ---------------- prep: split+swizzle weights; init mean/std ----------------
__global__ __launch_bounds__(256) void k_prep(const float* Wb, const float* Ws_,
                                              const float* Wa, const float* Wz,
                                              const float* Wr, float* ws) {
  int i = blockIdx.x * 256 + threadIdx.x;
  uint32_t* wsu = (uint32_t*)ws;
  if (i < 53248) {
    int d = i & 3; int t = i >> 2;
    int lane = t & 63; t >>= 6;
    int ks = t & 7; t >>= 3;
    int nt = t % 13; int hl = t / 13;
    int col = nt * 16 + (lane & 15);
    int kb = ks * 32 + (lane >> 4) * 8 + d * 2;
    uint32_t out = 0;
    for (int e = 0; e < 2; ++e) {
      int k = kb + e;
      float v = 0.f;
      if (col < 200) {
        if (k < 200)      v = Wb[k * 200 + col];
        else if (k < 230) v = Ws_[(k - 200) * 200 + col];
        else if (k < 236) v = Wa[(k - 230) * 200 + col];
      }
      uint32_t hi = bf16rne(v);
      float hf = __uint_as_float(hi << 16);
      uint32_t lo = bf16rne(v - hf);
      uint32_t bits = (hl == 0) ? hi : lo;
      out |= (bits & 0xFFFFu) << (16 * e);
    }
    wsu[OFF_WSW + i] = out;
  } else if (i < 60416) {
    int j = i - 53248;
    int d = j & 3; int t = j >> 2;
    int lane = t & 63; t >>= 6;
    int ks = t % 7; t /= 7;
    int nt = t & 1; int hl = t >> 1;
    int col = nt * 16 + (lane & 15);
    int kb = ks * 32 + (lane >> 4) * 8 + d * 2;
    uint32_t out = 0;
    for (int e = 0; e < 2; ++e) {
      int k = kb + e;
      float v = 0.f;
      if (k < 200) {
        if (col < 30)       v = Wz[k * 30 + col];
        else if (col == 30) v = Wr[k];       // merged reward: h·Wr via col 30
      }
      uint32_t hi = bf16rne(v);
      float hf = __uint_as_float(hi << 16);
      uint32_t lo = bf16rne(v - hf);
      uint32_t bits = (hl == 0) ? hi : lo;
      out |= (bits & 0xFFFFu) << (16 * e);
    }
    wsu[OFF_WZSW + j] = out;
  } else if (i >= 64512 && i < 66048) {
    ws[i] = 0.f;   // mean
  } else if (i >= 66048 && i < 67584) {
    ws[i] = 1.f;   // std
  }
}

// ---------------- full 12-step rollout via split-bf16 MFMA ----------------
// R10 geometry (proven 197us, absmax 0.0): 32 rows/block, 4 waves, grid 500.
// Per-element stage-1/stage-2 MFMA chains IDENTICAL to R10. Changes:
//  - reward folded into stage-2 (Wr in WZSW col 30): h·Wr from existing MFMA
//    chain (same products/order); s·Wr as per-lane VALU + one final butterfly.
//  - actions generated in-kernel (threefry bit-identical to k_actions) and
//    written to global ACT for selection.
//  - 4 barriers/step (was 6): [B0] s1-read |B1| h-write |B2| s2-read |B3|
//    s-write + act(t+1)-gen/write [B0].
__global__ __launch_bounds__(256) void k_roll(float* __restrict__ ws,
                                              const float* __restrict__ belief,
                                              const float* __restrict__ state,
                                              const float* __restrict__ bbp,
                                              const float* __restrict__ bzp,
                                              const float* __restrict__ brp,
                                              const float* __restrict__ wrp,
                                              uint32_t f0, uint32_t f1) {
  __shared__ unsigned short xh[32 * 280];   // bf16 hi
  __shared__ unsigned short xl[32 * 280];   // bf16 lo
  __shared__ float rp[4][16];               // per-wave reward partials

  const int tid = threadIdx.x;
  const int wv = tid >> 6;
  const int ln = tid & 63;
  const int r = ln & 15;
  const int kh = ln >> 4;
  const int grow0 = blockIdx.x * 32;
  const uint32_t* __restrict__ wsu = (const uint32_t*)ws;

  // stage-1 role (R7/R10 mapping)
  const int NT  = (wv == 0) ? 4 : 3;
  const int ntb = (wv == 0) ? 0 : (1 + wv * 3);
  // stage-2 role
  const int m2 = wv & 1, j2 = wv >> 1;

  float bbv[4];
#pragma unroll
  for (int j = 0; j < 4; ++j) {
    int col = (ntb + j) * 16 + r;
    bbv[j] = (j < NT && col < 200) ? bbp[col] : 0.f;
  }
  float bzz;
  {
    int col = j2 * 16 + r;
    bzz = (col < 30) ? bzp[col] : 0.f;
  }
  // reward s-weight for this wave's stage-2 column
  const float wr_s = (j2 == 0) ? wrp[200 + r] : ((r < 14) ? wrp[216 + r] : 0.f);
  const float br0 = brp[0];

  // init x: k<200 belief, 200..230 state, 236..256 zero (230..236 by act-gen)
  for (int idx = tid; idx < 32 * 256; idx += 256) {
    int row = idx >> 8, k = idx & 255;
    if (k >= 230 && k < 236) continue;      // actions written below (disjoint)
    int b = (grow0 + row) / 1000;
    float v = 0.f;
    if (k < 200) v = belief[b * 200 + k];
    else if (k < 230) v = state[b * 30 + (k - 200)];
    uint32_t hi = bf16rne(v);
    float hf = __uint_as_float(hi << 16);
    uint32_t lo = bf16rne(v - hf);
    xh[row * 280 + k] = (unsigned short)hi;
    xl[row * 280 + k] = (unsigned short)lo;
  }
  // t=0 actions: threefry in-kernel (bit-identical to k_actions)
  if (tid < 192) {
    int row = tid / 6, a = tid - row * 6;
    int growR = grow0 + row;
    int b = growR / 1000;
    uint32_t idx = (uint32_t)growR * 6u + (uint32_t)a;   // t=0
    uint32_t y0 = 0u, y1 = idx;
    tf2x32(f0, f1, y0, y1);
    float z = bits_to_normal(y0 ^ y1);
    float mu = ws[OFF_MEAN + (size_t)b * 8 + a];
    float sd = ws[OFF_STD + (size_t)b * 8 + a];
    float v = fmaf(sd, z, mu);
    ws[OFF_ACT + (size_t)growR * 8 + a] = v;
    uint32_t hi = bf16rne(v);
    float hf = __uint_as_float(hi << 16);
    uint32_t lo = bf16rne(v - hf);
    xh[row * 280 + 230 + a] = (unsigned short)hi;
    xl[row * 280 + 230 + a] = (unsigned short)lo;
  }
  __syncthreads();                           // B0(t=0): all writes complete

  float rps[4] = {0.f, 0.f, 0.f, 0.f};

#pragma unroll 1
  for (int t = 0; t < TT; ++t) {
    // ---- Phase A: stage 1 reads; h = x @ W_all + bb; 2 M-tiles x NT N-tiles ----
    f32x4 acc[2][4];
#pragma unroll
    for (int m = 0; m < 2; ++m)
#pragma unroll
      for (int j = 0; j < 4; ++j) {
        f32x4 c = {bbv[j], bbv[j], bbv[j], bbv[j]};
        acc[m][j] = c;
      }

#pragma unroll 2
    for (int ks = 0; ks < 8; ++ks) {
      short8v Ah[2], Al[2];
      const int kbase = ks * 32 + kh * 8;
#pragma unroll
      for (int m = 0; m < 2; ++m) {
        int off = (m * 16 + r) * 280 + kbase;
        Ah[m] = *(const short8v*)&xh[off];
        Al[m] = *(const short8v*)&xl[off];
      }
#pragma unroll
      for (int j = 0; j < 4; ++j) {
        if (j < NT) {
          const int nt = ntb + j;
          const short8v Bh = *(const short8v*)(wsu + OFF_WSW + (((0 * 13 + nt) * 8 + ks) * 64 + ln) * 4);
          const short8v Bl = *(const short8v*)(wsu + OFF_WSW + (((1 * 13 + nt) * 8 + ks) * 64 + ln) * 4);
#pragma unroll
          for (int m = 0; m < 2; ++m) {
            f32x4 c = acc[m][j];
            c = __builtin_amdgcn_mfma_f32_16x16x32_bf16(Al[m], Bl, c, 0, 0, 0);
            c = __builtin_amdgcn_mfma_f32_16x16x32_bf16(Ah[m], Bl, c, 0, 0, 0);
            c = __builtin_amdgcn_mfma_f32_16x16x32_bf16(Al[m], Bh, c, 0, 0, 0);
            c = __builtin_amdgcn_mfma_f32_16x16x32_bf16(Ah[m], Bh, c, 0, 0, 0);
            acc[m][j] = c;
          }
        }
      }
    }
    __syncthreads();                         // B1: all stage-1 reads done

    // ---- Phase B: h epilogue writes (D: row=(ln>>4)*4+reg, col=ln&15) ----
#pragma unroll
    for (int j = 0; j < 4; ++j) {
      int col = (ntb + j) * 16 + r;
      if (j < NT && col < 200) {
#pragma unroll
        for (int m = 0; m < 2; ++m) {
#pragma unroll
          for (int reg = 0; reg < 4; ++reg) {
            int row = m * 16 + kh * 4 + reg;
            float h = tanhf(acc[m][j][reg]);
            uint32_t hi = bf16rne(h);
            float hf = __uint_as_float(hi << 16);
            uint32_t lo = bf16rne(h - hf);
            xh[row * 280 + col] = (unsigned short)hi;
            xl[row * 280 + col] = (unsigned short)lo;
          }
        }
      }
    }
    __syncthreads();                         // B2: h writes complete

    // ---- Phase C: stage 2 reads; s-preact = h @ [Wz|Wr] + bz; unit (m2,j2) ----
    f32x4 acc2 = {bzz, bzz, bzz, bzz};
#pragma unroll
    for (int ks = 0; ks < 7; ++ks) {         // K=224; k>=200 weights are 0
      int off = (m2 * 16 + r) * 280 + ks * 32 + kh * 8;
      short8v Ah2 = *(const short8v*)&xh[off];
      short8v Al2 = *(const short8v*)&xl[off];
      const short8v Bh = *(const short8v*)(wsu + OFF_WZSW + (((0 * 2 + j2) * 7 + ks) * 64 + ln) * 4);
      const short8v Bl = *(const short8v*)(wsu + OFF_WZSW + (((1 * 2 + j2) * 7 + ks) * 64 + ln) * 4);
      acc2 = __builtin_amdgcn_mfma_f32_16x16x32_bf16(Al2, Bl, acc2, 0, 0, 0);
      acc2 = __builtin_amdgcn_mfma_f32_16x16x32_bf16(Ah2, Bl, acc2, 0, 0, 0);
      acc2 = __builtin_amdgcn_mfma_f32_16x16x32_bf16(Al2, Bh, acc2, 0, 0, 0);
      acc2 = __builtin_amdgcn_mfma_f32_16x16x32_bf16(Ah2, Bh, acc2, 0, 0, 0);
    }
    __syncthreads();                         // B3: all stage-2 reads done

    // ---- Phase D: s writes + reward partial + act(t+1) gen/write ----
    if (j2 == 0) {
      // cols 0..15 (all valid s)
#pragma unroll
      for (int reg = 0; reg < 4; ++reg) {
        int row = m2 * 16 + kh * 4 + reg;
        float s = tanhf(acc2[reg]);
        uint32_t hi = bf16rne(s);
        float hf = __uint_as_float(hi << 16);
        uint32_t lo = bf16rne(s - hf);
        xh[row * 280 + 200 + r] = (unsigned short)hi;
        xl[row * 280 + 200 + r] = (unsigned short)lo;
        rps[reg] = fmaf(s, wr_s, rps[reg]);
      }
    } else {
      if (r < 14) {
        // cols 16..29 (valid s)
#pragma unroll
        for (int reg = 0; reg < 4; ++reg) {
          int row = m2 * 16 + kh * 4 + reg;
          float s = tanhf(acc2[reg]);
          uint32_t hi = bf16rne(s);
          float hf = __uint_as_float(hi << 16);
          uint32_t lo = bf16rne(s - hf);
          xh[row * 280 + 216 + r] = (unsigned short)hi;
          xl[row * 280 + 216 + r] = (unsigned short)lo;
          rps[reg] = fmaf(s, wr_s, rps[reg]);
        }
      } else if (r == 14) {
        // col 30 = h·Wr (raw, no tanh) — the merged reward term
#pragma unroll
        for (int reg = 0; reg < 4; ++reg) rps[reg] += acc2[reg];
      }
    }
    // actions for t+1 (threefry, bit-identical; write LDS + global ACT)
    if (t + 1 < TT && tid < 192) {
      int row = tid / 6, a = tid - row * 6;
      int growR = grow0 + row;
      int b = growR / 1000;
      uint32_t idx = (uint32_t)((t + 1) * NROWS + growR) * 6u + (uint32_t)a;
      uint32_t y0 = 0u, y1 = idx;
      tf2x32(f0, f1, y0, y1);
      float z = bits_to_normal(y0 ^ y1);
      float mu = ws[OFF_MEAN + (((size_t)(t + 1) * 16 + b) * 8 + a)];
      float sd = ws[OFF_STD + (((size_t)(t + 1) * 16 + b) * 8 + a)];
      float v = fmaf(sd, z, mu);
      ws[OFF_ACT + ((size_t)(t + 1) * NROWS + growR) * 8 + a] = v;
      uint32_t hi = bf16rne(v);
      float hf = __uint_as_float(hi << 16);
      uint32_t lo = bf16rne(v - hf);
      xh[row * 280 + 230 + a] = (unsigned short)hi;
      xl[row * 280 + 230 + a] = (unsigned short)lo;
    }
    __syncthreads();                         // B0(t+1): all writes complete
  }

  // final reward reduction: butterfly over 16-lane groups, combine 2 waves/row
#pragma unroll
  for (int reg = 0; reg < 4; ++reg) {
#pragma unroll
    for (int mk = 1; mk < 16; mk <<= 1)
      rps[reg] += __shfl_xor(rps[reg], mk, 64);
  }
  if (r == 0) {
#pragma unroll
    for (int reg = 0; reg < 4; ++reg)
      rp[wv][kh * 4 + reg] = rps[reg];
  }
  __syncthreads();
  if (tid < 32) {
    int mrow = tid >> 4, lrow = tid & 15;
    ws[OFF_RET + grow0 + tid] = rp[mrow][lrow] + rp[2 + mrow][lrow] + 12.0f * br0;
  }
}

// ---------------- fused selection: bitonic top-k sort + mean/std ----------------
__global__ __launch_bounds__(1024) void k_select(float* ws) {
  __shared__ float sv[1024];
  __shared__ int si[1024];
  const int b = blockIdx.x, tid = threadIdx.x;
  const float* ret = ws + OFF_RET + b * 1000;
  sv[tid] = (tid < 1000) ? ret[tid] : -3.0e38f;
  si[tid] = tid;
  __syncthreads();
  for (int k = 2; k <= 1024; k <<= 1) {
    for (int j = k >> 1; j > 0; j >>= 1) {
      int ixj = tid ^ j;
      if (ixj > tid) {
        float v1 = sv[tid], v2 = sv[ixj];
        int i1 = si[tid], i2 = si[ixj];
        bool gt = (v1 < v2) || (v1 == v2 && i1 > i2);
        bool up = ((tid & k) == 0);
        if (up ? gt : !gt) {
          sv[tid] = v2; sv[ixj] = v1;
          si[tid] = i2; si[ixj] = i1;
        }
      }
      __syncthreads();
    }
  }
  // mean/std per (t,a): one wave per unit (verbatim k_meanstd reduction)
  const int wvS = tid >> 6, lnS = tid & 63;
  for (int u = wvS; u < 72; u += 16) {
    const int t = u / 6, a = u - t * 6;
    const float* act = ws + OFF_ACT + (size_t)t * NROWS * 8;
    const bool h2 = (lnS < 36);
    int c1 = si[lnS];
    float x1 = act[((size_t)b * 1000 + c1) * 8 + a];
    float x2 = 0.f;
    if (h2) { int cc = si[lnS + 64]; x2 = act[((size_t)b * 1000 + cc) * 8 + a]; }
    float s = x1 + x2;
#pragma unroll
    for (int m = 1; m < 64; m <<= 1) s += __shfl_xor(s, m, 64);
    const float mean = s / 100.0f;
    float d = x1 - mean; float qq = d * d;
    if (h2) { float d2 = x2 - mean; qq += d2 * d2; }
#pragma unroll
    for (int m = 1; m < 64; m <<= 1) qq += __shfl_xor(qq, m, 64);
    if (lnS == 0) {
      ws[OFF_MEAN + ((size_t)t * 16 + b) * 8 + a] = mean;
      ws[OFF_STD  + ((size_t)t * 16 + b) * 8 + a] = sqrtf(qq / 100.0f);
    }
  }
}

__global__ void k_out(const float* ws, float* out) {
  int i = threadIdx.x;
  if (i < 96) out[i] = ws[OFF_MEAN + (i / 6) * 8 + (i % 6)];
}

extern "C" void kernel_launch(void* const* d_in, const int* in_sizes, int n_in,
                              void* d_out, int out_size, void* d_ws, size_t ws_size,
                              hipStream_t stream) {
  const float* belief = (const float*)d_in[0];
  const float* state  = (const float*)d_in[1];
  const float* Wb  = (const float*)d_in[2];
  const float* Ws_ = (const float*)d_in[3];
  const float* Wa  = (const float*)d_in[4];
  const float* bb  = (const float*)d_in[5];
  const float* Wz  = (const float*)d_in[6];
  const float* bz  = (const float*)d_in[7];
  const float* Wr  = (const float*)d_in[8];
  const float* br  = (const float*)d_in[9];
  float* ws = (float*)d_ws;   // needs ~6.5 MB

  k_prep<<<264, 256, 0, stream>>>(Wb, Ws_, Wa, Wz, Wr, ws);

  for (int it = 0; it < NITERS; ++it) {
    uint32_t f0 = 0u, f1 = (uint32_t)it;
    tf2x32(0u, 42u, f0, f1);
    k_roll<<<500, 256, 0, stream>>>(ws, belief, state, bb, bz, br, Wr, f0, f1);
    k_select<<<16, 1024, 0, stream>>>(ws);
  }
  k_out<<<1, 128, 0, stream>>>(ws, (float*)d_out);
}

// Round 14
// 1435.598 us; speedup vs baseline: 1.9866x; 1.1893x over previous
//
#include <hip/hip_runtime.h>
#include <stdint.h>

#define TT 12
#define NITERS 10
#define NCAND 1000
#define AD 6
#define BD 16
#define HD 200
#define ZD 30
#define NROWS 16000
#define NELEM 1152000u

// ws layout (u32/float offsets)
#define OFF_WSW  0u          // u32[53248]  W_all split+swizzled B-frags [hl][13][8][64][4]
#define OFF_WZSW 53248u      // u32[7168]   [Wz | Wr_h@col30] [hl][2][7][64][4]
#define OFF_MEAN 64512u      // f32[12][16][8]
#define OFF_STD  66048u      // f32[12][16][8]
#define OFF_ACT  67584u      // f32[12][16000][8]
#define OFF_RET  1603584u    // f32[16000]

typedef __attribute__((ext_vector_type(8))) short short8v;
typedef __attribute__((ext_vector_type(4))) float f32x4;

// ---------------- threefry2x32 (JAX-exact) ----------------
__host__ __device__ __forceinline__ uint32_t tf_rotl(uint32_t x, int r) {
  return (x << r) | (x >> (32 - r));
}
__host__ __device__ __forceinline__ void tf2x32(uint32_t k0, uint32_t k1,
                                                uint32_t& x0, uint32_t& x1) {
  uint32_t k2 = k0 ^ k1 ^ 0x1BD11BDAu;
  x0 += k0; x1 += k1;
  x0 += x1; x1 = tf_rotl(x1, 13); x1 ^= x0;
  x0 += x1; x1 = tf_rotl(x1, 15); x1 ^= x0;
  x0 += x1; x1 = tf_rotl(x1, 26); x1 ^= x0;
  x0 += x1; x1 = tf_rotl(x1,  6); x1 ^= x0;
  x0 += k1; x1 += k2 + 1u;
  x0 += x1; x1 = tf_rotl(x1, 17); x1 ^= x0;
  x0 += x1; x1 = tf_rotl(x1, 29); x1 ^= x0;
  x0 += x1; x1 = tf_rotl(x1, 16); x1 ^= x0;
  x0 += x1; x1 = tf_rotl(x1, 24); x1 ^= x0;
  x0 += k2; x1 += k0 + 2u;
  x0 += x1; x1 = tf_rotl(x1, 13); x1 ^= x0;
  x0 += x1; x1 = tf_rotl(x1, 15); x1 ^= x0;
  x0 += x1; x1 = tf_rotl(x1, 26); x1 ^= x0;
  x0 += x1; x1 = tf_rotl(x1,  6); x1 ^= x0;
  x0 += k0; x1 += k1 + 3u;
  x0 += x1; x1 = tf_rotl(x1, 17); x1 ^= x0;
  x0 += x1; x1 = tf_rotl(x1, 29); x1 ^= x0;
  x0 += x1; x1 = tf_rotl(x1, 16); x1 ^= x0;
  x0 += x1; x1 = tf_rotl(x1, 24); x1 ^= x0;
  x0 += k1; x1 += k2 + 4u;
  x0 += x1; x1 = tf_rotl(x1, 13); x1 ^= x0;
  x0 += x1; x1 = tf_rotl(x1, 15); x1 ^= x0;
  x0 += x1; x1 = tf_rotl(x1, 26); x1 ^= x0;
  x0 += x1; x1 = tf_rotl(x1,  6); x1 ^= x0;
  x0 += k2; x1 += k0 + 5u;
}

__device__ __forceinline__ float bits_to_normal(uint32_t bits) {
  uint32_t fb = (bits >> 9) | 0x3F800000u;
  float f = __uint_as_float(fb) - 1.0f;          // [0,1)
  float u = f * 2.0f - 0.99999994f;
  u = fmaxf(-0.99999994f, u);
  float w = -log1pf(-u * u);
  float p;
  if (w < 5.0f) {
    w = w - 2.5f;
    p = 2.81022636e-08f;
    p = fmaf(p, w, 3.43273939e-07f);
    p = fmaf(p, w, -3.5233877e-06f);
    p = fmaf(p, w, -4.39150654e-06f);
    p = fmaf(p, w, 0.00021858087f);
    p = fmaf(p, w, -0.00125372503f);
    p = fmaf(p, w, -0.00417768164f);
    p = fmaf(p, w, 0.246640727f);
    p = fmaf(p, w, 1.50140941f);
  } else {
    w = sqrtf(w) - 3.0f;
    p = -0.000200214257f;
    p = fmaf(p, w, 0.000100950558f);
    p = fmaf(p, w, 0.00134934322f);
    p = fmaf(p, w, -0.00367342844f);
    p = fmaf(p, w, 0.00573950773f);
    p = fmaf(p, w, -0.0076224613f);
    p = fmaf(p, w, 0.00943887047f);
    p = fmaf(p, w, 1.00167406f);
    p = fmaf(p, w, 2.83297682f);
  }
  return 1.41421354f * (p * u);
}

// bf16 round-to-nearest-even (returns 16-bit pattern)
__device__ __forceinline__ uint32_t bf16rne(float x) {
  uint32_t u = __float_as_uint(x);
  return (u + 0x7FFFu + ((u >> 16) & 1u)) >> 16;
}

// fast tanh: Eigen/XLA-style rational approx x*P(x2)/Q(x2), |err|~1e-7 rel.
// (perturbation ~100x below the split-bf16 class the elite cascade survives)
__device__ __forceinline__ float fast_tanh(float x) {
  x = fmaxf(-7.90531110763549805f, fminf(7.90531110763549805f, x));
  float x2 = x * x;
  float p = -2.76076847742355e-16f;
  p = fmaf(x2, p, 2.00018790482477e-13f);
  p = fmaf(x2, p, -8.60467152213735e-11f);
  p = fmaf(x2, p, 5.12229709037114e-08f);
  p = fmaf(x2, p, 1.48572235717979e-05f);
  p = fmaf(x2, p, 6.37261928875436e-04f);
  p = fmaf(x2, p, 4.89352455891786e-03f);
  p = x * p;
  float q = 1.19825839466702e-06f;
  q = fmaf(x2, q, 1.18534705686654e-04f);
  q = fmaf(x2, q, 2.26843774817441e-03f);
  q = fmaf(x2, q, 4.89352518554385e-03f);
  return p * __builtin_amdgcn_rcpf(q);
}

// ---------------- prep: split+swizzle weights; init mean/std ----------------
__global__ __launch_bounds__(256) void k_prep(const float* Wb, const float* Ws_,
                                              const float* Wa, const float* Wz,
                                              const float* Wr, float* ws) {
  int i = blockIdx.x * 256 + threadIdx.x;
  uint32_t* wsu = (uint32_t*)ws;
  if (i < 53248) {
    int d = i & 3; int t = i >> 2;
    int lane = t & 63; t >>= 6;
    int ks = t & 7; t >>= 3;
    int nt = t % 13; int hl = t / 13;
    int col = nt * 16 + (lane & 15);
    int kb = ks * 32 + (lane >> 4) * 8 + d * 2;
    uint32_t out = 0;
    for (int e = 0; e < 2; ++e) {
      int k = kb + e;
      float v = 0.f;
      if (col < 200) {
        if (k < 200)      v = Wb[k * 200 + col];
        else if (k < 230) v = Ws_[(k - 200) * 200 + col];
        else if (k < 236) v = Wa[(k - 230) * 200 + col];
      }
      uint32_t hi = bf16rne(v);
      float hf = __uint_as_float(hi << 16);
      uint32_t lo = bf16rne(v - hf);
      uint32_t bits = (hl == 0) ? hi : lo;
      out |= (bits & 0xFFFFu) << (16 * e);
    }
    wsu[OFF_WSW + i] = out;
  } else if (i < 60416) {
    int j = i - 53248;
    int d = j & 3; int t = j >> 2;
    int lane = t & 63; t >>= 6;
    int ks = t % 7; t /= 7;
    int nt = t & 1; int hl = t >> 1;
    int col = nt * 16 + (lane & 15);
    int kb = ks * 32 + (lane >> 4) * 8 + d * 2;
    uint32_t out = 0;
    for (int e = 0; e < 2; ++e) {
      int k = kb + e;
      float v = 0.f;
      if (k < 200) {
        if (col < 30)       v = Wz[k * 30 + col];
        else if (col == 30) v = Wr[k];       // merged reward: h·Wr via col 30
      }
      uint32_t hi = bf16rne(v);
      float hf = __uint_as_float(hi << 16);
      uint32_t lo = bf16rne(v - hf);
      uint32_t bits = (hl == 0) ? hi : lo;
      out |= (bits & 0xFFFFu) << (16 * e);
    }
    wsu[OFF_WZSW + j] = out;
  } else if (i >= 64512 && i < 66048) {
    ws[i] = 0.f;   // mean
  } else if (i >= 66048 && i < 67584) {
    ws[i] = 1.f;   // std
  }
}

// ---------------- full 12-step rollout via split-bf16 MFMA (3-pass) ----------------
// R13 structure verbatim (proven absmax 0.0) with two perturbation-class cuts:
//  - 3-pass: Al·Bl (~2^-18 relative) dropped from every chain.
//  - fast_tanh rational approx (~1e-7 relative) replaces tanhf.
// Phases: [B0] s1-read |B1| h-write |B2| s2-read |B3| s-write+act(t+1) [B0].
__global__ __launch_bounds__(256) void k_roll(float* __restrict__ ws,
                                              const float* __restrict__ belief,
                                              const float* __restrict__ state,
                                              const float* __restrict__ bbp,
                                              const float* __restrict__ bzp,
                                              const float* __restrict__ brp,
                                              const float* __restrict__ wrp,
                                              uint32_t f0, uint32_t f1) {
  __shared__ unsigned short xh[32 * 280];   // bf16 hi
  __shared__ unsigned short xl[32 * 280];   // bf16 lo
  __shared__ float rp[4][16];               // per-wave reward partials

  const int tid = threadIdx.x;
  const int wv = tid >> 6;
  const int ln = tid & 63;
  const int r = ln & 15;
  const int kh = ln >> 4;
  const int grow0 = blockIdx.x * 32;
  const uint32_t* __restrict__ wsu = (const uint32_t*)ws;

  // stage-1 role (R7/R10 mapping)
  const int NT  = (wv == 0) ? 4 : 3;
  const int ntb = (wv == 0) ? 0 : (1 + wv * 3);
  // stage-2 role
  const int m2 = wv & 1, j2 = wv >> 1;

  float bbv[4];
#pragma unroll
  for (int j = 0; j < 4; ++j) {
    int col = (ntb + j) * 16 + r;
    bbv[j] = (j < NT && col < 200) ? bbp[col] : 0.f;
  }
  float bzz;
  {
    int col = j2 * 16 + r;
    bzz = (col < 30) ? bzp[col] : 0.f;
  }
  // reward s-weight for this wave's stage-2 column
  const float wr_s = (j2 == 0) ? wrp[200 + r] : ((r < 14) ? wrp[216 + r] : 0.f);
  const float br0 = brp[0];

  // init x: k<200 belief, 200..230 state, 236..256 zero (230..236 by act-gen)
  for (int idx = tid; idx < 32 * 256; idx += 256) {
    int row = idx >> 8, k = idx & 255;
    if (k >= 230 && k < 236) continue;      // actions written below (disjoint)
    int b = (grow0 + row) / 1000;
    float v = 0.f;
    if (k < 200) v = belief[b * 200 + k];
    else if (k < 230) v = state[b * 30 + (k - 200)];
    uint32_t hi = bf16rne(v);
    float hf = __uint_as_float(hi << 16);
    uint32_t lo = bf16rne(v - hf);
    xh[row * 280 + k] = (unsigned short)hi;
    xl[row * 280 + k] = (unsigned short)lo;
  }
  // t=0 actions: threefry in-kernel (bit-identical to reference PRNG)
  if (tid < 192) {
    int row = tid / 6, a = tid - row * 6;
    int growR = grow0 + row;
    int b = growR / 1000;
    uint32_t idx = (uint32_t)growR * 6u + (uint32_t)a;   // t=0
    uint32_t y0 = 0u, y1 = idx;
    tf2x32(f0, f1, y0, y1);
    float z = bits_to_normal(y0 ^ y1);
    float mu = ws[OFF_MEAN + (size_t)b * 8 + a];
    float sd = ws[OFF_STD + (size_t)b * 8 + a];
    float v = fmaf(sd, z, mu);
    ws[OFF_ACT + (size_t)growR * 8 + a] = v;
    uint32_t hi = bf16rne(v);
    float hf = __uint_as_float(hi << 16);
    uint32_t lo = bf16rne(v - hf);
    xh[row * 280 + 230 + a] = (unsigned short)hi;
    xl[row * 280 + 230 + a] = (unsigned short)lo;
  }
  __syncthreads();                           // B0(t=0): all writes complete

  float rps[4] = {0.f, 0.f, 0.f, 0.f};

#pragma unroll 1
  for (int t = 0; t < TT; ++t) {
    // ---- Phase A: stage 1 reads; h = x @ W_all + bb; 2 M-tiles x NT N-tiles ----
    f32x4 acc[2][4];
#pragma unroll
    for (int m = 0; m < 2; ++m)
#pragma unroll
      for (int j = 0; j < 4; ++j) {
        f32x4 c = {bbv[j], bbv[j], bbv[j], bbv[j]};
        acc[m][j] = c;
      }

#pragma unroll 2
    for (int ks = 0; ks < 8; ++ks) {
      short8v Ah[2], Al[2];
      const int kbase = ks * 32 + kh * 8;
#pragma unroll
      for (int m = 0; m < 2; ++m) {
        int off = (m * 16 + r) * 280 + kbase;
        Ah[m] = *(const short8v*)&xh[off];
        Al[m] = *(const short8v*)&xl[off];
      }
#pragma unroll
      for (int j = 0; j < 4; ++j) {
        if (j < NT) {
          const int nt = ntb + j;
          const short8v Bh = *(const short8v*)(wsu + OFF_WSW + (((0 * 13 + nt) * 8 + ks) * 64 + ln) * 4);
          const short8v Bl = *(const short8v*)(wsu + OFF_WSW + (((1 * 13 + nt) * 8 + ks) * 64 + ln) * 4);
#pragma unroll
          for (int m = 0; m < 2; ++m) {
            f32x4 c = acc[m][j];
            c = __builtin_amdgcn_mfma_f32_16x16x32_bf16(Ah[m], Bl, c, 0, 0, 0);
            c = __builtin_amdgcn_mfma_f32_16x16x32_bf16(Al[m], Bh, c, 0, 0, 0);
            c = __builtin_amdgcn_mfma_f32_16x16x32_bf16(Ah[m], Bh, c, 0, 0, 0);
            acc[m][j] = c;
          }
        }
      }
    }
    __syncthreads();                         // B1: all stage-1 reads done

    // ---- Phase B: h epilogue writes (D: row=(ln>>4)*4+reg, col=ln&15) ----
#pragma unroll
    for (int j = 0; j < 4; ++j) {
      int col = (ntb + j) * 16 + r;
      if (j < NT && col < 200) {
#pragma unroll
        for (int m = 0; m < 2; ++m) {
#pragma unroll
          for (int reg = 0; reg < 4; ++reg) {
            int row = m * 16 + kh * 4 + reg;
            float h = fast_tanh(acc[m][j][reg]);
            uint32_t hi = bf16rne(h);
            float hf = __uint_as_float(hi << 16);
            uint32_t lo = bf16rne(h - hf);
            xh[row * 280 + col] = (unsigned short)hi;
            xl[row * 280 + col] = (unsigned short)lo;
          }
        }
      }
    }
    __syncthreads();                         // B2: h writes complete

    // ---- Phase C: stage 2 reads; s-preact = h @ [Wz|Wr] + bz; unit (m2,j2) ----
    f32x4 acc2 = {bzz, bzz, bzz, bzz};
#pragma unroll
    for (int ks = 0; ks < 7; ++ks) {         // K=224; k>=200 weights are 0
      int off = (m2 * 16 + r) * 280 + ks * 32 + kh * 8;
      short8v Ah2 = *(const short8v*)&xh[off];
      short8v Al2 = *(const short8v*)&xl[off];
      const short8v Bh = *(const short8v*)(wsu + OFF_WZSW + (((0 * 2 + j2) * 7 + ks) * 64 + ln) * 4);
      const short8v Bl = *(const short8v*)(wsu + OFF_WZSW + (((1 * 2 + j2) * 7 + ks) * 64 + ln) * 4);
      acc2 = __builtin_amdgcn_mfma_f32_16x16x32_bf16(Ah2, Bl, acc2, 0, 0, 0);
      acc2 = __builtin_amdgcn_mfma_f32_16x16x32_bf16(Al2, Bh, acc2, 0, 0, 0);
      acc2 = __builtin_amdgcn_mfma_f32_16x16x32_bf16(Ah2, Bh, acc2, 0, 0, 0);
    }
    __syncthreads();                         // B3: all stage-2 reads done

    // ---- Phase D: s writes + reward partial + act(t+1) gen/write ----
    if (j2 == 0) {
      // cols 0..15 (all valid s)
#pragma unroll
      for (int reg = 0; reg < 4; ++reg) {
        int row = m2 * 16 + kh * 4 + reg;
        float s = fast_tanh(acc2[reg]);
        uint32_t hi = bf16rne(s);
        float hf = __uint_as_float(hi << 16);
        uint32_t lo = bf16rne(s - hf);
        xh[row * 280 + 200 + r] = (unsigned short)hi;
        xl[row * 280 + 200 + r] = (unsigned short)lo;
        rps[reg] = fmaf(s, wr_s, rps[reg]);
      }
    } else {
      if (r < 14) {
        // cols 16..29 (valid s)
#pragma unroll
        for (int reg = 0; reg < 4; ++reg) {
          int row = m2 * 16 + kh * 4 + reg;
          float s = fast_tanh(acc2[reg]);
          uint32_t hi = bf16rne(s);
          float hf = __uint_as_float(hi << 16);
          uint32_t lo = bf16rne(s - hf);
          xh[row * 280 + 216 + r] = (unsigned short)hi;
          xl[row * 280 + 216 + r] = (unsigned short)lo;
          rps[reg] = fmaf(s, wr_s, rps[reg]);
        }
      } else if (r == 14) {
        // col 30 = h·Wr (raw, no tanh) — the merged reward term
#pragma unroll
        for (int reg = 0; reg < 4; ++reg) rps[reg] += acc2[reg];
      }
    }
    // actions for t+1 (threefry, bit-identical; write LDS + global ACT)
    if (t + 1 < TT && tid < 192) {
      int row = tid / 6, a = tid - row * 6;
      int growR = grow0 + row;
      int b = growR / 1000;
      uint32_t idx = (uint32_t)((t + 1) * NROWS + growR) * 6u + (uint32_t)a;
      uint32_t y0 = 0u, y1 = idx;
      tf2x32(f0, f1, y0, y1);
      float z = bits_to_normal(y0 ^ y1);
      float mu = ws[OFF_MEAN + (((size_t)(t + 1) * 16 + b) * 8 + a)];
      float sd = ws[OFF_STD + (((size_t)(t + 1) * 16 + b) * 8 + a)];
      float v = fmaf(sd, z, mu);
      ws[OFF_ACT + ((size_t)(t + 1) * NROWS + growR) * 8 + a] = v;
      uint32_t hi = bf16rne(v);
      float hf = __uint_as_float(hi << 16);
      uint32_t lo = bf16rne(v - hf);
      xh[row * 280 + 230 + a] = (unsigned short)hi;
      xl[row * 280 + 230 + a] = (unsigned short)lo;
    }
    __syncthreads();                         // B0(t+1): all writes complete
  }

  // final reward reduction: butterfly over 16-lane groups, combine 2 waves/row
#pragma unroll
  for (int reg = 0; reg < 4; ++reg) {
#pragma unroll
    for (int mk = 1; mk < 16; mk <<= 1)
      rps[reg] += __shfl_xor(rps[reg], mk, 64);
  }
  if (r == 0) {
#pragma unroll
    for (int reg = 0; reg < 4; ++reg)
      rp[wv][kh * 4 + reg] = rps[reg];
  }
  __syncthreads();
  if (tid < 32) {
    int mrow = tid >> 4, lrow = tid & 15;
    ws[OFF_RET + grow0 + tid] = rp[mrow][lrow] + rp[2 + mrow][lrow] + 12.0f * br0;
  }
}

// ---------------- fused selection: bitonic top-k sort + mean/std ----------------
__global__ __launch_bounds__(1024) void k_select(float* ws) {
  __shared__ float sv[1024];
  __shared__ int si[1024];
  const int b = blockIdx.x, tid = threadIdx.x;
  const float* ret = ws + OFF_RET + b * 1000;
  sv[tid] = (tid < 1000) ? ret[tid] : -3.0e38f;
  si[tid] = tid;
  __syncthreads();
  for (int k = 2; k <= 1024; k <<= 1) {
    for (int j = k >> 1; j > 0; j >>= 1) {
      int ixj = tid ^ j;
      if (ixj > tid) {
        float v1 = sv[tid], v2 = sv[ixj];
        int i1 = si[tid], i2 = si[ixj];
        bool gt = (v1 < v2) || (v1 == v2 && i1 > i2);
        bool up = ((tid & k) == 0);
        if (up ? gt : !gt) {
          sv[tid] = v2; sv[ixj] = v1;
          si[tid] = i2; si[ixj] = i1;
        }
      }
      __syncthreads();
    }
  }
  // mean/std per (t,a): one wave per unit (verbatim k_meanstd reduction)
  const int wvS = tid >> 6, lnS = tid & 63;
  for (int u = wvS; u < 72; u += 16) {
    const int t = u / 6, a = u - t * 6;
    const float* act = ws + OFF_ACT + (size_t)t * NROWS * 8;
    const bool h2 = (lnS < 36);
    int c1 = si[lnS];
    float x1 = act[((size_t)b * 1000 + c1) * 8 + a];
    float x2 = 0.f;
    if (h2) { int cc = si[lnS + 64]; x2 = act[((size_t)b * 1000 + cc) * 8 + a]; }
    float s = x1 + x2;
#pragma unroll
    for (int m = 1; m < 64; m <<= 1) s += __shfl_xor(s, m, 64);
    const float mean = s / 100.0f;
    float d = x1 - mean; float qq = d * d;
    if (h2) { float d2 = x2 - mean; qq += d2 * d2; }
#pragma unroll
    for (int m = 1; m < 64; m <<= 1) qq += __shfl_xor(qq, m, 64);
    if (lnS == 0) {
      ws[OFF_MEAN + ((size_t)t * 16 + b) * 8 + a] = mean;
      ws[OFF_STD  + ((size_t)t * 16 + b) * 8 + a] = sqrtf(qq / 100.0f);
    }
  }
}

__global__ void k_out(const float* ws, float* out) {
  int i = threadIdx.x;
  if (i < 96) out[i] = ws[OFF_MEAN + (i / 6) * 8 + (i % 6)];
}

extern "C" void kernel_launch(void* const* d_in, const int* in_sizes, int n_in,
                              void* d_out, int out_size, void* d_ws, size_t ws_size,
                              hipStream_t stream) {
  const float* belief = (const float*)d_in[0];
  const float* state  = (const float*)d_in[1];
  const float* Wb  = (const float*)d_in[2];
  const float* Ws_ = (const float*)d_in[3];
  const float* Wa  = (const float*)d_in[4];
  const float* bb  = (const float*)d_in[5];
  const float* Wz  = (const float*)d_in[6];
  const float* bz  = (const float*)d_in[7];
  const float* Wr  = (const float*)d_in[8];
  const float* br  = (const float*)d_in[9];
  float* ws = (float*)d_ws;   // needs ~6.5 MB

  k_prep<<<264, 256, 0, stream>>>(Wb, Ws_, Wa, Wz, Wr, ws);

  for (int it = 0; it < NITERS; ++it) {
    uint32_t f0 = 0u, f1 = (uint32_t)it;
    tf2x32(0u, 42u, f0, f1);
    k_roll<<<500, 256, 0, stream>>>(ws, belief, state, bb, bz, br, Wr, f0, f1);
    k_select<<<16, 1024, 0, stream>>>(ws);
  }
  k_out<<<1, 128, 0, stream>>>(ws, (float*)d_out);
}